// Round 1
// baseline (608.543 us; speedup 1.0000x reference)
//
#include <hip/hip_runtime.h>

#define NMET 200000
#define NRXN 400000
#define ESUB 800000
#define EALL 1600000

// c_target = BASELINE * (1 + CIRC_AMP * sin(2*pi*FRAME/PERIOD))
//          = 1 + 0.5*sin(0.2*pi) = 1.2938926261462366
#define C_TARGET 1.29389262614623664f
#define DT_C 0.01f
#define HOMEO_C 0.1f
#define LOG2_10 3.32192809488736235f

__device__ __forceinline__ float fast_tanh(float x) {
    float e = __expf(2.0f * x);          // v_exp based
    return 1.0f - 2.0f / (e + 1.0f);     // exact at +/- saturation
}

// ---------------- kernel 1: per-substrate-edge MLP + segment accumulate ----
__global__ __launch_bounds__(256) void k_edge_msg(
    const float* __restrict__ x, const int* __restrict__ met_sub,
    const int* __restrict__ rxn_sub, const float* __restrict__ sto_sub,
    const float* __restrict__ sub_w1, const float* __restrict__ sub_b1,
    const float* __restrict__ sub_w2, const float* __restrict__ sub_b2,
    float* __restrict__ h_rxn, float* __restrict__ ext_sum, float* __restrict__ cnt)
{
    __shared__ float sW1[128];
    __shared__ float sB1[64];
    __shared__ __align__(16) float sW2[512];
    __shared__ float sB2[8];
    int t = threadIdx.x;
    for (int i = t; i < 128; i += 256) sW1[i] = sub_w1[i];
    for (int i = t; i < 64;  i += 256) sB1[i] = sub_b1[i];
    for (int i = t; i < 512; i += 256) sW2[i] = sub_w2[i];
    if (t < 8) sB2[t] = sub_b2[t];
    __syncthreads();

    int e = blockIdx.x * 256 + t;
    if (e >= ESUB) return;
    int m = met_sub[e];
    int r = rxn_sub[e];
    float c = x[(size_t)m * 8 + 3];
    float ex = x[(size_t)m * 8 + 4] * 2.0f;
    float s = sto_sub[e];

    float m0 = sB2[0], m1 = sB2[1], m2 = sB2[2], m3 = sB2[3];
    float m4 = sB2[4], m5 = sB2[5], m6 = sB2[6], m7 = sB2[7];
    #pragma unroll 8
    for (int j = 0; j < 64; ++j) {
        float z = fmaf(c, sW1[j], fmaf(s, sW1[64 + j], sB1[j]));
        float h = fast_tanh(z);
        float4 wa = *(const float4*)&sW2[j * 8];
        float4 wb = *(const float4*)&sW2[j * 8 + 4];
        m0 = fmaf(h, wa.x, m0); m1 = fmaf(h, wa.y, m1);
        m2 = fmaf(h, wa.z, m2); m3 = fmaf(h, wa.w, m3);
        m4 = fmaf(h, wb.x, m4); m5 = fmaf(h, wb.y, m5);
        m6 = fmaf(h, wb.z, m6); m7 = fmaf(h, wb.w, m7);
    }
    float* hr = &h_rxn[(size_t)r * 8];
    atomicAdd(&hr[0], m0); atomicAdd(&hr[1], m1);
    atomicAdd(&hr[2], m2); atomicAdd(&hr[3], m3);
    atomicAdd(&hr[4], m4); atomicAdd(&hr[5], m5);
    atomicAdd(&hr[6], m6); atomicAdd(&hr[7], m7);
    atomicAdd(&ext_sum[r], ex);
    atomicAdd(&cnt[r], 1.0f);
}

// ---------------- kernel 2: per-reaction rate MLP -> v; init rxn_scale -----
__global__ __launch_bounds__(256) void k_rxn(
    const float* __restrict__ h_rxn, const float* __restrict__ ext_sum,
    const float* __restrict__ cnt, const float* __restrict__ log_k,
    const float* __restrict__ rate_w1, const float* __restrict__ rate_b1,
    const float* __restrict__ rate_w2, const float* __restrict__ rate_b2,
    float* __restrict__ v, float* __restrict__ rxn_scale)
{
    __shared__ __align__(16) float sW1[512];
    __shared__ float sB1[64];
    __shared__ float sW2[64];
    __shared__ float sB2;
    int t = threadIdx.x;
    for (int i = t; i < 512; i += 256) sW1[i] = rate_w1[i];
    if (t < 64) sB1[t] = rate_b1[t];
    else if (t < 128) sW2[t - 64] = rate_w2[t - 64];
    if (t == 192) sB2 = rate_b2[0];
    __syncthreads();

    int r = blockIdx.x * 256 + t;
    if (r >= NRXN) return;
    float4 ha = *(const float4*)&h_rxn[(size_t)r * 8];
    float4 hb = *(const float4*)&h_rxn[(size_t)r * 8 + 4];
    float acc = sB2;
    #pragma unroll 4
    for (int j = 0; j < 64; ++j) {
        float z = sB1[j];
        z = fmaf(ha.x, sW1[j],       z);
        z = fmaf(ha.y, sW1[64 + j],  z);
        z = fmaf(ha.z, sW1[128 + j], z);
        z = fmaf(ha.w, sW1[192 + j], z);
        z = fmaf(hb.x, sW1[256 + j], z);
        z = fmaf(hb.y, sW1[320 + j], z);
        z = fmaf(hb.z, sW1[384 + j], z);
        z = fmaf(hb.w, sW1[448 + j], z);
        acc = fmaf(fast_tanh(z), sW2[j], acc);
    }
    float n = fmaxf(cnt[r], 1.0f);
    float k = exp2f(log_k[r] * LOG2_10);
    v[r] = k * (ext_sum[r] / n) * acc;
    rxn_scale[r] = 1.0f;
}

// ---------------- kernel 3: consumption scatter ----------------------------
__global__ __launch_bounds__(256) void k_consume(
    const int* __restrict__ met_sub, const int* __restrict__ rxn_sub,
    const float* __restrict__ sto_sub, const float* __restrict__ v,
    float* __restrict__ total)
{
    int e = blockIdx.x * 256 + threadIdx.x;
    if (e >= ESUB) return;
    atomicAdd(&total[met_sub[e]], sto_sub[e] * v[rxn_sub[e]] * DT_C);
}

// ---------------- kernel 4: per-metabolite scale + out init ----------------
__global__ __launch_bounds__(256) void k_met(
    const float* __restrict__ x, const float* __restrict__ total,
    float* __restrict__ met_scale, float* __restrict__ out)
{
    int m = blockIdx.x * 256 + threadIdx.x;
    if (m >= NMET) return;
    float c = x[(size_t)m * 8 + 3];
    float tot = total[m];
    float ms = 1.0f;
    if (tot > 1e-12f) ms = fminf(c / tot, 1.0f);
    met_scale[m] = ms;
    out[m] = -HOMEO_C * (c - C_TARGET);
}

// ---------------- kernel 5: segment-min scatter (uint-bits atomicMin) ------
__global__ __launch_bounds__(256) void k_rmin(
    const int* __restrict__ met_sub, const int* __restrict__ rxn_sub,
    const float* __restrict__ met_scale, float* __restrict__ rxn_scale)
{
    int e = blockIdx.x * 256 + threadIdx.x;
    if (e >= ESUB) return;
    unsigned int bits = __float_as_uint(met_scale[met_sub[e]]);
    atomicMin((unsigned int*)&rxn_scale[rxn_sub[e]], bits);
}

// ---------------- kernel 6: v *= rxn_scale ---------------------------------
__global__ __launch_bounds__(256) void k_vscale(
    float* __restrict__ v, const float* __restrict__ rxn_scale)
{
    int r = blockIdx.x * 256 + threadIdx.x;
    if (r >= NRXN) return;
    v[r] *= rxn_scale[r];
}

// ---------------- kernel 7: final scatter-add into out ---------------------
__global__ __launch_bounds__(256) void k_contrib(
    const int* __restrict__ met_all, const int* __restrict__ rxn_all,
    const float* __restrict__ sto_all, const float* __restrict__ v,
    float* __restrict__ out)
{
    int e = blockIdx.x * 256 + threadIdx.x;
    if (e >= EALL) return;
    atomicAdd(&out[met_all[e]], sto_all[e] * v[rxn_all[e]]);
}

extern "C" void kernel_launch(void* const* d_in, const int* in_sizes, int n_in,
                              void* d_out, int out_size, void* d_ws, size_t ws_size,
                              hipStream_t stream) {
    const float* x       = (const float*)d_in[0];
    const int*   met_sub = (const int*)  d_in[1];
    const int*   rxn_sub = (const int*)  d_in[2];
    const float* sto_sub = (const float*)d_in[3];
    const int*   met_all = (const int*)  d_in[4];
    const int*   rxn_all = (const int*)  d_in[5];
    const float* sto_all = (const float*)d_in[6];
    const float* sub_w1  = (const float*)d_in[7];
    const float* sub_b1  = (const float*)d_in[8];
    const float* sub_w2  = (const float*)d_in[9];
    const float* sub_b2  = (const float*)d_in[10];
    const float* rate_w1 = (const float*)d_in[11];
    const float* rate_b1 = (const float*)d_in[12];
    const float* rate_w2 = (const float*)d_in[13];
    const float* rate_b2 = (const float*)d_in[14];
    const float* log_k   = (const float*)d_in[15];

    float* ws        = (float*)d_ws;
    float* h_rxn     = ws;                              // NRXN*8
    float* ext_sum   = h_rxn + (size_t)NRXN * 8;        // NRXN
    float* cnt       = ext_sum + NRXN;                  // NRXN
    float* total     = cnt + NRXN;                      // NMET
    float* v         = total + NMET;                    // NRXN
    float* rxn_scale = v + NRXN;                        // NRXN
    float* met_scale = rxn_scale + NRXN;                // NMET
    float* out       = (float*)d_out;

    // zero the atomic accumulators (h_rxn, ext_sum, cnt, total are contiguous)
    size_t zero_bytes = ((size_t)NRXN * 8 + NRXN + NRXN + NMET) * sizeof(float);
    hipMemsetAsync(d_ws, 0, zero_bytes, stream);

    dim3 blk(256);
    k_edge_msg<<<dim3((ESUB + 255) / 256), blk, 0, stream>>>(
        x, met_sub, rxn_sub, sto_sub, sub_w1, sub_b1, sub_w2, sub_b2,
        h_rxn, ext_sum, cnt);
    k_rxn<<<dim3((NRXN + 255) / 256), blk, 0, stream>>>(
        h_rxn, ext_sum, cnt, log_k, rate_w1, rate_b1, rate_w2, rate_b2,
        v, rxn_scale);
    k_consume<<<dim3((ESUB + 255) / 256), blk, 0, stream>>>(
        met_sub, rxn_sub, sto_sub, v, total);
    k_met<<<dim3((NMET + 255) / 256), blk, 0, stream>>>(
        x, total, met_scale, out);
    k_rmin<<<dim3((ESUB + 255) / 256), blk, 0, stream>>>(
        met_sub, rxn_sub, met_scale, rxn_scale);
    k_vscale<<<dim3((NRXN + 255) / 256), blk, 0, stream>>>(
        v, rxn_scale);
    k_contrib<<<dim3((EALL + 255) / 256), blk, 0, stream>>>(
        met_all, rxn_all, sto_all, v, out);
}

// Round 2
// 365.899 us; speedup vs baseline: 1.6631x; 1.6631x over previous
//
#include <hip/hip_runtime.h>

#define NMET 200000
#define NRXN 400000
#define ESUB 800000
#define EALL 1600000
#define NBLK ((NRXN + 255) / 256)   // 1563 scan blocks

// c_target = 1 + 0.5*sin(2*pi*100/1000) = 1.2938926261462366
#define C_TARGET 1.29389262614623664f
#define DT_C 0.01f
#define HOMEO_C 0.1f
#define LOG2_10 3.32192809488736235f

__device__ __forceinline__ float fast_tanh(float x) {
    float e = __expf(2.0f * x);
    return 1.0f - 2.0f / (e + 1.0f);
}

// ---- 1. histogram over rxn_sub; rank[e] = arrival order within reaction ----
__global__ __launch_bounds__(256) void k_hist(
    const int* __restrict__ rxn_sub, int* __restrict__ cnt, int* __restrict__ rank)
{
    int e = blockIdx.x * 256 + threadIdx.x;
    if (e >= ESUB) return;
    rank[e] = atomicAdd(&cnt[rxn_sub[e]], 1);
}

// ---- 2. per-256-block sums of cnt ------------------------------------------
__global__ __launch_bounds__(256) void k_bsum(
    const int* __restrict__ cnt, int* __restrict__ bsum)
{
    __shared__ int lds[256];
    int i = blockIdx.x * 256 + threadIdx.x;
    lds[threadIdx.x] = (i < NRXN) ? cnt[i] : 0;
    __syncthreads();
    for (int off = 128; off > 0; off >>= 1) {
        if (threadIdx.x < off) lds[threadIdx.x] += lds[threadIdx.x + off];
        __syncthreads();
    }
    if (threadIdx.x == 0) bsum[blockIdx.x] = lds[0];
}

// ---- 3. single-block exclusive scan of the block sums ----------------------
__global__ __launch_bounds__(256) void k_scan_top(
    const int* __restrict__ bsum, int* __restrict__ boff, int nb)
{
    __shared__ int lds[256];
    __shared__ int carry_s;
    if (threadIdx.x == 0) carry_s = 0;
    __syncthreads();
    for (int base = 0; base < nb; base += 256) {
        int i = base + threadIdx.x;
        int val = (i < nb) ? bsum[i] : 0;
        lds[threadIdx.x] = val;
        __syncthreads();
        for (int off = 1; off < 256; off <<= 1) {
            int add = (threadIdx.x >= off) ? lds[threadIdx.x - off] : 0;
            __syncthreads();
            lds[threadIdx.x] += add;
            __syncthreads();
        }
        int incl = lds[threadIdx.x];
        int carry = carry_s;
        if (i < nb) boff[i] = carry + incl - val;
        __syncthreads();
        if (threadIdx.x == 255) carry_s = carry + incl;
        __syncthreads();
    }
}

// ---- 4. per-reaction global offsets (block scan + boff) --------------------
__global__ __launch_bounds__(256) void k_offsets(
    const int* __restrict__ cnt, const int* __restrict__ boff, int* __restrict__ offset)
{
    __shared__ int lds[256];
    int i = blockIdx.x * 256 + threadIdx.x;
    int val = (i < NRXN) ? cnt[i] : 0;
    lds[threadIdx.x] = val;
    __syncthreads();
    for (int off = 1; off < 256; off <<= 1) {
        int add = (threadIdx.x >= off) ? lds[threadIdx.x - off] : 0;
        __syncthreads();
        lds[threadIdx.x] += add;
        __syncthreads();
    }
    if (i < NRXN) offset[i] = boff[blockIdx.x] + lds[threadIdx.x] - val;
}

// ---- 5. scatter edge ids into CSR slots (no atomics) -----------------------
__global__ __launch_bounds__(256) void k_scatter(
    const int* __restrict__ rxn_sub, const int* __restrict__ offset,
    const int* __restrict__ rank, int* __restrict__ slot_edge)
{
    int e = blockIdx.x * 256 + threadIdx.x;
    if (e >= ESUB) return;
    slot_edge[offset[rxn_sub[e]] + rank[e]] = e;
}

// ---- 6. per-reaction: gather edges, edge-MLP, rate-MLP, v ------------------
__global__ __launch_bounds__(256) void k_rxn2(
    const float* __restrict__ x, const int* __restrict__ met_sub,
    const float* __restrict__ sto_sub,
    const int* __restrict__ cnt, const int* __restrict__ offset,
    const int* __restrict__ slot_edge,
    const float* __restrict__ sub_w1, const float* __restrict__ sub_b1,
    const float* __restrict__ sub_w2, const float* __restrict__ sub_b2,
    const float* __restrict__ rate_w1, const float* __restrict__ rate_b1,
    const float* __restrict__ rate_w2, const float* __restrict__ rate_b2,
    const float* __restrict__ log_k, float* __restrict__ v)
{
    __shared__ float sW1[128];
    __shared__ float sB1[64];
    __shared__ __align__(16) float sW2[512];
    __shared__ float sB2[8];
    __shared__ __align__(16) float sR1[512];
    __shared__ float sRB1[64];
    __shared__ float sR2[64];
    __shared__ float sRB2;
    int t = threadIdx.x;
    for (int i = t; i < 128; i += 256) sW1[i] = sub_w1[i];
    for (int i = t; i < 64;  i += 256) sB1[i] = sub_b1[i];
    for (int i = t; i < 512; i += 256) sW2[i] = sub_w2[i];
    if (t < 8) sB2[t] = sub_b2[t];
    for (int i = t; i < 512; i += 256) sR1[i] = rate_w1[i];
    for (int i = t; i < 64;  i += 256) { sRB1[i] = rate_b1[i]; sR2[i] = rate_w2[i]; }
    if (t == 64) sRB2 = rate_b2[0];
    __syncthreads();

    int r = blockIdx.x * 256 + t;
    if (r >= NRXN) return;
    int n = cnt[r];
    int base = offset[r];

    float h0 = 0.f, h1 = 0.f, h2 = 0.f, h3 = 0.f;
    float h4 = 0.f, h5 = 0.f, h6 = 0.f, h7 = 0.f;
    float exs = 0.f;
    for (int i = 0; i < n; ++i) {
        int e = slot_edge[base + i];
        int m = met_sub[e];
        float c = x[(size_t)m * 8 + 3];
        exs += x[(size_t)m * 8 + 4];
        float s = sto_sub[e];
        #pragma unroll 8
        for (int j = 0; j < 64; ++j) {
            float z = fmaf(c, sW1[j], fmaf(s, sW1[64 + j], sB1[j]));
            float th = fast_tanh(z);
            float4 wa = *(const float4*)&sW2[j * 8];
            float4 wb = *(const float4*)&sW2[j * 8 + 4];
            h0 = fmaf(th, wa.x, h0); h1 = fmaf(th, wa.y, h1);
            h2 = fmaf(th, wa.z, h2); h3 = fmaf(th, wa.w, h3);
            h4 = fmaf(th, wb.x, h4); h5 = fmaf(th, wb.y, h5);
            h6 = fmaf(th, wb.z, h6); h7 = fmaf(th, wb.w, h7);
        }
    }
    float fn = (float)n;
    h0 = fmaf(fn, sB2[0], h0); h1 = fmaf(fn, sB2[1], h1);
    h2 = fmaf(fn, sB2[2], h2); h3 = fmaf(fn, sB2[3], h3);
    h4 = fmaf(fn, sB2[4], h4); h5 = fmaf(fn, sB2[5], h5);
    h6 = fmaf(fn, sB2[6], h6); h7 = fmaf(fn, sB2[7], h7);

    float acc = sRB2;
    #pragma unroll 4
    for (int j = 0; j < 64; ++j) {
        float z = sRB1[j];
        z = fmaf(h0, sR1[j],       z);
        z = fmaf(h1, sR1[64 + j],  z);
        z = fmaf(h2, sR1[128 + j], z);
        z = fmaf(h3, sR1[192 + j], z);
        z = fmaf(h4, sR1[256 + j], z);
        z = fmaf(h5, sR1[320 + j], z);
        z = fmaf(h6, sR1[384 + j], z);
        z = fmaf(h7, sR1[448 + j], z);
        acc = fmaf(fast_tanh(z), sR2[j], acc);
    }
    float nmax = fmaxf(fn, 1.0f);
    float ext_mean = 2.0f * exs / nmax;
    float kk = exp2f(log_k[r] * LOG2_10);
    v[r] = kk * ext_mean * acc;
}

// ---- 7. consumption scatter (met-keyed, keep atomics) ----------------------
__global__ __launch_bounds__(256) void k_consume(
    const int* __restrict__ met_sub, const int* __restrict__ rxn_sub,
    const float* __restrict__ sto_sub, const float* __restrict__ v,
    float* __restrict__ total)
{
    int e = blockIdx.x * 256 + threadIdx.x;
    if (e >= ESUB) return;
    atomicAdd(&total[met_sub[e]], sto_sub[e] * v[rxn_sub[e]] * DT_C);
}

// ---- 8. per-metabolite scale + out init ------------------------------------
__global__ __launch_bounds__(256) void k_met(
    const float* __restrict__ x, const float* __restrict__ total,
    float* __restrict__ met_scale, float* __restrict__ out)
{
    int m = blockIdx.x * 256 + threadIdx.x;
    if (m >= NMET) return;
    float c = x[(size_t)m * 8 + 3];
    float tot = total[m];
    float ms = 1.0f;
    if (tot > 1e-12f) ms = fminf(c / tot, 1.0f);
    met_scale[m] = ms;
    out[m] = -HOMEO_C * (c - C_TARGET);
}

// ---- 9. per-reaction min over edges (CSR gather) + v scale -----------------
__global__ __launch_bounds__(256) void k_rscale(
    const int* __restrict__ met_sub, const int* __restrict__ cnt,
    const int* __restrict__ offset, const int* __restrict__ slot_edge,
    const float* __restrict__ met_scale, float* __restrict__ v)
{
    int r = blockIdx.x * 256 + threadIdx.x;
    if (r >= NRXN) return;
    int n = cnt[r];
    int base = offset[r];
    float ms = 1.0f;
    for (int i = 0; i < n; ++i) {
        int e = slot_edge[base + i];
        ms = fminf(ms, met_scale[met_sub[e]]);
    }
    v[r] *= ms;
}

// ---- 10. final scatter-add -------------------------------------------------
__global__ __launch_bounds__(256) void k_contrib(
    const int* __restrict__ met_all, const int* __restrict__ rxn_all,
    const float* __restrict__ sto_all, const float* __restrict__ v,
    float* __restrict__ out)
{
    int e = blockIdx.x * 256 + threadIdx.x;
    if (e >= EALL) return;
    atomicAdd(&out[met_all[e]], sto_all[e] * v[rxn_all[e]]);
}

extern "C" void kernel_launch(void* const* d_in, const int* in_sizes, int n_in,
                              void* d_out, int out_size, void* d_ws, size_t ws_size,
                              hipStream_t stream) {
    const float* x       = (const float*)d_in[0];
    const int*   met_sub = (const int*)  d_in[1];
    const int*   rxn_sub = (const int*)  d_in[2];
    const float* sto_sub = (const float*)d_in[3];
    const int*   met_all = (const int*)  d_in[4];
    const int*   rxn_all = (const int*)  d_in[5];
    const float* sto_all = (const float*)d_in[6];
    const float* sub_w1  = (const float*)d_in[7];
    const float* sub_b1  = (const float*)d_in[8];
    const float* sub_w2  = (const float*)d_in[9];
    const float* sub_b2  = (const float*)d_in[10];
    const float* rate_w1 = (const float*)d_in[11];
    const float* rate_b1 = (const float*)d_in[12];
    const float* rate_w2 = (const float*)d_in[13];
    const float* rate_b2 = (const float*)d_in[14];
    const float* log_k   = (const float*)d_in[15];

    char* ws = (char*)d_ws;
    int*   cnt       = (int*)ws;                         // NRXN   [zeroed]
    float* total     = (float*)(cnt + NRXN);             // NMET   [zeroed]
    int*   rank      = (int*)(total + NMET);             // ESUB
    int*   offset    = rank + ESUB;                      // NRXN
    int*   bsum      = offset + NRXN;                    // 2048
    int*   boff      = bsum + 2048;                      // 2048
    int*   slot_edge = boff + 2048;                      // ESUB
    float* v         = (float*)(slot_edge + ESUB);       // NRXN
    float* met_scale = v + NRXN;                         // NMET
    float* out       = (float*)d_out;

    // zero atomic accumulators: cnt + total are contiguous
    hipMemsetAsync(d_ws, 0, (size_t)(NRXN + NMET) * sizeof(int), stream);

    dim3 blk(256);
    k_hist<<<dim3((ESUB + 255) / 256), blk, 0, stream>>>(rxn_sub, cnt, rank);
    k_bsum<<<dim3(NBLK), blk, 0, stream>>>(cnt, bsum);
    k_scan_top<<<dim3(1), blk, 0, stream>>>(bsum, boff, NBLK);
    k_offsets<<<dim3(NBLK), blk, 0, stream>>>(cnt, boff, offset);
    k_scatter<<<dim3((ESUB + 255) / 256), blk, 0, stream>>>(rxn_sub, offset, rank, slot_edge);
    k_rxn2<<<dim3((NRXN + 255) / 256), blk, 0, stream>>>(
        x, met_sub, sto_sub, cnt, offset, slot_edge,
        sub_w1, sub_b1, sub_w2, sub_b2,
        rate_w1, rate_b1, rate_w2, rate_b2, log_k, v);
    k_consume<<<dim3((ESUB + 255) / 256), blk, 0, stream>>>(
        met_sub, rxn_sub, sto_sub, v, total);
    k_met<<<dim3((NMET + 255) / 256), blk, 0, stream>>>(x, total, met_scale, out);
    k_rscale<<<dim3((NRXN + 255) / 256), blk, 0, stream>>>(
        met_sub, cnt, offset, slot_edge, met_scale, v);
    k_contrib<<<dim3((EALL + 255) / 256), blk, 0, stream>>>(
        met_all, rxn_all, sto_all, v, out);
}

// Round 3
// 261.772 us; speedup vs baseline: 2.3247x; 1.3978x over previous
//
#include <hip/hip_runtime.h>

#define NMET 200000
#define NRXN 400000
#define ESUB 800000
#define EALL 1600000
#define NBLK ((NRXN + 255) / 256)   // 1563 scan blocks

// c_target = 1 + 0.5*sin(2*pi*100/1000) = 1.2938926261462366
#define C_TARGET 1.29389262614623664f
#define DT_C 0.01f
#define HOMEO_C 0.1f
#define LOG2_10 3.32192809488736235f

__device__ __forceinline__ float fast_tanh(float x) {
    float e = __expf(2.0f * x);
    return 1.0f - 2.0f * __builtin_amdgcn_rcpf(e + 1.0f);
}

// ---- 1. histogram over rxn_sub; rank[e] = arrival order within reaction ----
__global__ __launch_bounds__(256) void k_hist(
    const int* __restrict__ rxn_sub, int* __restrict__ cnt, int* __restrict__ rank)
{
    int e = blockIdx.x * 256 + threadIdx.x;
    if (e >= ESUB) return;
    rank[e] = atomicAdd(&cnt[rxn_sub[e]], 1);
}

// ---- 2. per-256-block sums of cnt ------------------------------------------
__global__ __launch_bounds__(256) void k_bsum(
    const int* __restrict__ cnt, int* __restrict__ bsum)
{
    __shared__ int lds[256];
    int i = blockIdx.x * 256 + threadIdx.x;
    lds[threadIdx.x] = (i < NRXN) ? cnt[i] : 0;
    __syncthreads();
    for (int off = 128; off > 0; off >>= 1) {
        if (threadIdx.x < off) lds[threadIdx.x] += lds[threadIdx.x + off];
        __syncthreads();
    }
    if (threadIdx.x == 0) bsum[blockIdx.x] = lds[0];
}

// ---- 3. single-block exclusive scan of the block sums ----------------------
__global__ __launch_bounds__(256) void k_scan_top(
    const int* __restrict__ bsum, int* __restrict__ boff, int nb)
{
    __shared__ int lds[256];
    __shared__ int carry_s;
    if (threadIdx.x == 0) carry_s = 0;
    __syncthreads();
    for (int base = 0; base < nb; base += 256) {
        int i = base + threadIdx.x;
        int val = (i < nb) ? bsum[i] : 0;
        lds[threadIdx.x] = val;
        __syncthreads();
        for (int off = 1; off < 256; off <<= 1) {
            int add = (threadIdx.x >= off) ? lds[threadIdx.x - off] : 0;
            __syncthreads();
            lds[threadIdx.x] += add;
            __syncthreads();
        }
        int incl = lds[threadIdx.x];
        int carry = carry_s;
        if (i < nb) boff[i] = carry + incl - val;
        __syncthreads();
        if (threadIdx.x == 255) carry_s = carry + incl;
        __syncthreads();
    }
}

// ---- 4. per-reaction global offsets (block scan + boff) --------------------
__global__ __launch_bounds__(256) void k_offsets(
    const int* __restrict__ cnt, const int* __restrict__ boff, int* __restrict__ offset)
{
    __shared__ int lds[256];
    int i = blockIdx.x * 256 + threadIdx.x;
    int val = (i < NRXN) ? cnt[i] : 0;
    lds[threadIdx.x] = val;
    __syncthreads();
    for (int off = 1; off < 256; off <<= 1) {
        int add = (threadIdx.x >= off) ? lds[threadIdx.x - off] : 0;
        __syncthreads();
        lds[threadIdx.x] += add;
        __syncthreads();
    }
    if (i < NRXN) offset[i] = boff[blockIdx.x] + lds[threadIdx.x] - val;
}

// ---- 5. edge-parallel MLP, write message into CSR slot ---------------------
__global__ __launch_bounds__(256) void k_msg(
    const float* __restrict__ x, const int* __restrict__ met_sub,
    const int* __restrict__ rxn_sub, const float* __restrict__ sto_sub,
    const int* __restrict__ offset, const int* __restrict__ rank,
    const float* __restrict__ sub_w1, const float* __restrict__ sub_b1,
    const float* __restrict__ sub_w2,
    float* __restrict__ msg, float* __restrict__ exts,
    int* __restrict__ met_slot, float* __restrict__ sto_slot)
{
    __shared__ float sW1[128];
    __shared__ float sB1[64];
    __shared__ __align__(16) float sW2[512];
    int t = threadIdx.x;
    for (int i = t; i < 128; i += 256) sW1[i] = sub_w1[i];
    for (int i = t; i < 64;  i += 256) sB1[i] = sub_b1[i];
    for (int i = t; i < 512; i += 256) sW2[i] = sub_w2[i];
    __syncthreads();

    int e = blockIdx.x * 256 + t;
    if (e >= ESUB) return;
    int r = rxn_sub[e];
    int m = met_sub[e];
    float st = sto_sub[e];
    float c  = x[(size_t)m * 8 + 3];
    float ex = x[(size_t)m * 8 + 4];
    int s = offset[r] + rank[e];

    float m0 = 0.f, m1 = 0.f, m2 = 0.f, m3 = 0.f;
    float m4 = 0.f, m5 = 0.f, m6 = 0.f, m7 = 0.f;
    #pragma unroll 8
    for (int j = 0; j < 64; ++j) {
        float z = fmaf(c, sW1[j], fmaf(st, sW1[64 + j], sB1[j]));
        float th = fast_tanh(z);
        float4 wa = *(const float4*)&sW2[j * 8];
        float4 wb = *(const float4*)&sW2[j * 8 + 4];
        m0 = fmaf(th, wa.x, m0); m1 = fmaf(th, wa.y, m1);
        m2 = fmaf(th, wa.z, m2); m3 = fmaf(th, wa.w, m3);
        m4 = fmaf(th, wb.x, m4); m5 = fmaf(th, wb.y, m5);
        m6 = fmaf(th, wb.z, m6); m7 = fmaf(th, wb.w, m7);
    }
    float4* mp = (float4*)&msg[(size_t)s * 8];
    mp[0] = make_float4(m0, m1, m2, m3);
    mp[1] = make_float4(m4, m5, m6, m7);
    exts[s] = ex;
    met_slot[s] = m;
    sto_slot[s] = st;
}

// ---- 6. per-reaction: gather contiguous msgs, rate MLP, v, consume ---------
__global__ __launch_bounds__(256) void k_rxn3(
    const int* __restrict__ cnt, const int* __restrict__ offset,
    const float* __restrict__ msg, const float* __restrict__ exts,
    const int* __restrict__ met_slot, const float* __restrict__ sto_slot,
    const float* __restrict__ sub_b2,
    const float* __restrict__ rate_w1, const float* __restrict__ rate_b1,
    const float* __restrict__ rate_w2, const float* __restrict__ rate_b2,
    const float* __restrict__ log_k,
    float* __restrict__ v, float* __restrict__ total)
{
    __shared__ __align__(16) float sR1[512];
    __shared__ float sRB1[64];
    __shared__ float sR2[64];
    __shared__ float sB2[8];
    __shared__ float sRB2;
    int t = threadIdx.x;
    for (int i = t; i < 512; i += 256) sR1[i] = rate_w1[i];
    for (int i = t; i < 64;  i += 256) { sRB1[i] = rate_b1[i]; sR2[i] = rate_w2[i]; }
    if (t < 8) sB2[t] = sub_b2[t];
    if (t == 64) sRB2 = rate_b2[0];
    __syncthreads();

    int r = blockIdx.x * 256 + t;
    if (r >= NRXN) return;
    int n = cnt[r];
    int base = offset[r];
    float fn = (float)n;

    float h0 = fn * sB2[0], h1 = fn * sB2[1], h2 = fn * sB2[2], h3 = fn * sB2[3];
    float h4 = fn * sB2[4], h5 = fn * sB2[5], h6 = fn * sB2[6], h7 = fn * sB2[7];
    float exs = 0.f;
    for (int i = 0; i < n; ++i) {
        const float4* mp = (const float4*)&msg[(size_t)(base + i) * 8];
        float4 a = mp[0], b = mp[1];
        h0 += a.x; h1 += a.y; h2 += a.z; h3 += a.w;
        h4 += b.x; h5 += b.y; h6 += b.z; h7 += b.w;
        exs += exts[base + i];
    }

    float acc = sRB2;
    #pragma unroll 4
    for (int j = 0; j < 64; ++j) {
        float z = sRB1[j];
        z = fmaf(h0, sR1[j],       z);
        z = fmaf(h1, sR1[64 + j],  z);
        z = fmaf(h2, sR1[128 + j], z);
        z = fmaf(h3, sR1[192 + j], z);
        z = fmaf(h4, sR1[256 + j], z);
        z = fmaf(h5, sR1[320 + j], z);
        z = fmaf(h6, sR1[384 + j], z);
        z = fmaf(h7, sR1[448 + j], z);
        acc = fmaf(fast_tanh(z), sR2[j], acc);
    }
    float nmax = fmaxf(fn, 1.0f);
    float ext_mean = 2.0f * exs * __builtin_amdgcn_rcpf(nmax);
    float kk = exp2f(log_k[r] * LOG2_10);
    float vr = kk * ext_mean * acc;
    v[r] = vr;

    // consumption scatter (uses pre-limit v, per reference)
    float cterm = vr * DT_C;
    for (int i = 0; i < n; ++i) {
        int s = base + i;
        atomicAdd(&total[met_slot[s]], sto_slot[s] * cterm);
    }
}

// ---- 7. per-metabolite scale + out init ------------------------------------
__global__ __launch_bounds__(256) void k_met(
    const float* __restrict__ x, const float* __restrict__ total,
    float* __restrict__ met_scale, float* __restrict__ out)
{
    int m = blockIdx.x * 256 + threadIdx.x;
    if (m >= NMET) return;
    float c = x[(size_t)m * 8 + 3];
    float tot = total[m];
    float ms = 1.0f;
    if (tot > 1e-12f) ms = fminf(c / tot, 1.0f);
    met_scale[m] = ms;
    out[m] = -HOMEO_C * (c - C_TARGET);
}

// ---- 8. per-reaction min over edges (contiguous slots) + v scale -----------
__global__ __launch_bounds__(256) void k_rscale(
    const int* __restrict__ cnt, const int* __restrict__ offset,
    const int* __restrict__ met_slot, const float* __restrict__ met_scale,
    float* __restrict__ v)
{
    int r = blockIdx.x * 256 + threadIdx.x;
    if (r >= NRXN) return;
    int n = cnt[r];
    int base = offset[r];
    float ms = 1.0f;
    for (int i = 0; i < n; ++i)
        ms = fminf(ms, met_scale[met_slot[base + i]]);
    v[r] *= ms;
}

// ---- 9. final scatter-add --------------------------------------------------
__global__ __launch_bounds__(256) void k_contrib(
    const int* __restrict__ met_all, const int* __restrict__ rxn_all,
    const float* __restrict__ sto_all, const float* __restrict__ v,
    float* __restrict__ out)
{
    int e = blockIdx.x * 256 + threadIdx.x;
    if (e >= EALL) return;
    atomicAdd(&out[met_all[e]], sto_all[e] * v[rxn_all[e]]);
}

extern "C" void kernel_launch(void* const* d_in, const int* in_sizes, int n_in,
                              void* d_out, int out_size, void* d_ws, size_t ws_size,
                              hipStream_t stream) {
    const float* x       = (const float*)d_in[0];
    const int*   met_sub = (const int*)  d_in[1];
    const int*   rxn_sub = (const int*)  d_in[2];
    const float* sto_sub = (const float*)d_in[3];
    const int*   met_all = (const int*)  d_in[4];
    const int*   rxn_all = (const int*)  d_in[5];
    const float* sto_all = (const float*)d_in[6];
    const float* sub_w1  = (const float*)d_in[7];
    const float* sub_b1  = (const float*)d_in[8];
    const float* sub_w2  = (const float*)d_in[9];
    const float* sub_b2  = (const float*)d_in[10];
    const float* rate_w1 = (const float*)d_in[11];
    const float* rate_b1 = (const float*)d_in[12];
    const float* rate_w2 = (const float*)d_in[13];
    const float* rate_b2 = (const float*)d_in[14];
    const float* log_k   = (const float*)d_in[15];

    char* ws = (char*)d_ws;
    int*   cnt       = (int*)ws;                         // NRXN   [zeroed]
    float* total     = (float*)(cnt + NRXN);             // NMET   [zeroed]
    int*   rank      = (int*)(total + NMET);             // ESUB
    int*   offset    = rank + ESUB;                      // NRXN
    int*   bsum      = offset + NRXN;                    // 2048
    int*   boff      = bsum + 2048;                      // 2048
    float* msg       = (float*)(boff + 2048);            // ESUB*8
    float* exts      = msg + (size_t)ESUB * 8;           // ESUB
    int*   met_slot  = (int*)(exts + ESUB);              // ESUB
    float* sto_slot  = (float*)(met_slot + ESUB);        // ESUB
    float* v         = sto_slot + ESUB;                  // NRXN
    float* met_scale = v + NRXN;                         // NMET
    float* out       = (float*)d_out;

    // zero atomic accumulators: cnt + total are contiguous
    hipMemsetAsync(d_ws, 0, (size_t)(NRXN + NMET) * sizeof(int), stream);

    dim3 blk(256);
    k_hist<<<dim3((ESUB + 255) / 256), blk, 0, stream>>>(rxn_sub, cnt, rank);
    k_bsum<<<dim3(NBLK), blk, 0, stream>>>(cnt, bsum);
    k_scan_top<<<dim3(1), blk, 0, stream>>>(bsum, boff, NBLK);
    k_offsets<<<dim3(NBLK), blk, 0, stream>>>(cnt, boff, offset);
    k_msg<<<dim3((ESUB + 255) / 256), blk, 0, stream>>>(
        x, met_sub, rxn_sub, sto_sub, offset, rank,
        sub_w1, sub_b1, sub_w2, msg, exts, met_slot, sto_slot);
    k_rxn3<<<dim3((NRXN + 255) / 256), blk, 0, stream>>>(
        cnt, offset, msg, exts, met_slot, sto_slot, sub_b2,
        rate_w1, rate_b1, rate_w2, rate_b2, log_k, v, total);
    k_met<<<dim3((NMET + 255) / 256), blk, 0, stream>>>(x, total, met_scale, out);
    k_rscale<<<dim3((NRXN + 255) / 256), blk, 0, stream>>>(
        cnt, offset, met_slot, met_scale, v);
    k_contrib<<<dim3((EALL + 255) / 256), blk, 0, stream>>>(
        met_all, rxn_all, sto_all, v, out);
}

// Round 4
// 253.089 us; speedup vs baseline: 2.4045x; 1.0343x over previous
//
#include <hip/hip_runtime.h>

#define NMET 200000
#define NRXN 400000
#define ESUB 800000
#define EALL 1600000
#define NBLK ((NRXN + 255) / 256)   // 1563 scan blocks

// c_target = 1 + 0.5*sin(2*pi*100/1000) = 1.2938926261462366
#define C_TARGET 1.29389262614623664f
#define DT_C 0.01f
#define HOMEO_C 0.1f
#define LOG2_10 3.32192809488736235f

__device__ __forceinline__ float fast_tanh(float x) {
    float e = __expf(2.0f * x);
    return 1.0f - 2.0f * __builtin_amdgcn_rcpf(e + 1.0f);
}

// ---- 1. fused: histogram atomic (wall) + edge MLP (hidden under it) --------
// msg/ext_e written in EDGE order -> fully coalesced stores.
__global__ __launch_bounds__(256) void k_hist_msg(
    const float* __restrict__ x, const int* __restrict__ met_sub,
    const int* __restrict__ rxn_sub, const float* __restrict__ sto_sub,
    const float* __restrict__ sub_w1, const float* __restrict__ sub_b1,
    const float* __restrict__ sub_w2,
    int* __restrict__ cnt, int* __restrict__ rank,
    float* __restrict__ msg, float* __restrict__ ext_e)
{
    __shared__ float sW1[128];
    __shared__ float sB1[64];
    __shared__ __align__(16) float sW2[512];
    int t = threadIdx.x;
    for (int i = t; i < 128; i += 256) sW1[i] = sub_w1[i];
    for (int i = t; i < 64;  i += 256) sB1[i] = sub_b1[i];
    for (int i = t; i < 512; i += 256) sW2[i] = sub_w2[i];
    __syncthreads();

    int e = blockIdx.x * 256 + t;
    if (e >= ESUB) return;
    int r = rxn_sub[e];
    // issue the atomic early; MLP compute hides under its latency/drain
    rank[e] = atomicAdd(&cnt[r], 1);

    int m = met_sub[e];
    float st = sto_sub[e];
    float c  = x[(size_t)m * 8 + 3];
    float ex = x[(size_t)m * 8 + 4];

    float m0 = 0.f, m1 = 0.f, m2 = 0.f, m3 = 0.f;
    float m4 = 0.f, m5 = 0.f, m6 = 0.f, m7 = 0.f;
    #pragma unroll 8
    for (int j = 0; j < 64; ++j) {
        float z = fmaf(c, sW1[j], fmaf(st, sW1[64 + j], sB1[j]));
        float th = fast_tanh(z);
        float4 wa = *(const float4*)&sW2[j * 8];
        float4 wb = *(const float4*)&sW2[j * 8 + 4];
        m0 = fmaf(th, wa.x, m0); m1 = fmaf(th, wa.y, m1);
        m2 = fmaf(th, wa.z, m2); m3 = fmaf(th, wa.w, m3);
        m4 = fmaf(th, wb.x, m4); m5 = fmaf(th, wb.y, m5);
        m6 = fmaf(th, wb.z, m6); m7 = fmaf(th, wb.w, m7);
    }
    float4* mp = (float4*)&msg[(size_t)e * 8];
    mp[0] = make_float4(m0, m1, m2, m3);
    mp[1] = make_float4(m4, m5, m6, m7);
    ext_e[e] = ex;
}

// ---- 2. per-256-block sums of cnt ------------------------------------------
__global__ __launch_bounds__(256) void k_bsum(
    const int* __restrict__ cnt, int* __restrict__ bsum)
{
    __shared__ int lds[256];
    int i = blockIdx.x * 256 + threadIdx.x;
    lds[threadIdx.x] = (i < NRXN) ? cnt[i] : 0;
    __syncthreads();
    for (int off = 128; off > 0; off >>= 1) {
        if (threadIdx.x < off) lds[threadIdx.x] += lds[threadIdx.x + off];
        __syncthreads();
    }
    if (threadIdx.x == 0) bsum[blockIdx.x] = lds[0];
}

// ---- 3. single-block exclusive scan of the block sums ----------------------
__global__ __launch_bounds__(256) void k_scan_top(
    const int* __restrict__ bsum, int* __restrict__ boff, int nb)
{
    __shared__ int lds[256];
    __shared__ int carry_s;
    if (threadIdx.x == 0) carry_s = 0;
    __syncthreads();
    for (int base = 0; base < nb; base += 256) {
        int i = base + threadIdx.x;
        int val = (i < nb) ? bsum[i] : 0;
        lds[threadIdx.x] = val;
        __syncthreads();
        for (int off = 1; off < 256; off <<= 1) {
            int add = (threadIdx.x >= off) ? lds[threadIdx.x - off] : 0;
            __syncthreads();
            lds[threadIdx.x] += add;
            __syncthreads();
        }
        int incl = lds[threadIdx.x];
        int carry = carry_s;
        if (i < nb) boff[i] = carry + incl - val;
        __syncthreads();
        if (threadIdx.x == 255) carry_s = carry + incl;
        __syncthreads();
    }
}

// ---- 4. per-reaction global offsets (block scan + boff) --------------------
__global__ __launch_bounds__(256) void k_offsets(
    const int* __restrict__ cnt, const int* __restrict__ boff, int* __restrict__ offset)
{
    __shared__ int lds[256];
    int i = blockIdx.x * 256 + threadIdx.x;
    int val = (i < NRXN) ? cnt[i] : 0;
    lds[threadIdx.x] = val;
    __syncthreads();
    for (int off = 1; off < 256; off <<= 1) {
        int add = (threadIdx.x >= off) ? lds[threadIdx.x - off] : 0;
        __syncthreads();
        lds[threadIdx.x] += add;
        __syncthreads();
    }
    if (i < NRXN) offset[i] = boff[blockIdx.x] + lds[threadIdx.x] - val;
}

// ---- 5. scatter edge ids into CSR slots (plain stores) ---------------------
__global__ __launch_bounds__(256) void k_scatter(
    const int* __restrict__ rxn_sub, const int* __restrict__ offset,
    const int* __restrict__ rank, int* __restrict__ slot_edge)
{
    int e = blockIdx.x * 256 + threadIdx.x;
    if (e >= ESUB) return;
    slot_edge[offset[rxn_sub[e]] + rank[e]] = e;
}

// ---- 6. per-reaction: gather msgs via slot_edge, rate MLP, v, consume ------
__global__ __launch_bounds__(256) void k_rxn3(
    const int* __restrict__ cnt, const int* __restrict__ offset,
    const int* __restrict__ slot_edge,
    const float* __restrict__ msg, const float* __restrict__ ext_e,
    const int* __restrict__ met_sub, const float* __restrict__ sto_sub,
    const float* __restrict__ sub_b2,
    const float* __restrict__ rate_w1, const float* __restrict__ rate_b1,
    const float* __restrict__ rate_w2, const float* __restrict__ rate_b2,
    const float* __restrict__ log_k,
    float* __restrict__ v, float* __restrict__ total)
{
    __shared__ __align__(16) float sR1[512];
    __shared__ float sRB1[64];
    __shared__ float sR2[64];
    __shared__ float sB2[8];
    __shared__ float sRB2;
    int t = threadIdx.x;
    for (int i = t; i < 512; i += 256) sR1[i] = rate_w1[i];
    for (int i = t; i < 64;  i += 256) { sRB1[i] = rate_b1[i]; sR2[i] = rate_w2[i]; }
    if (t < 8) sB2[t] = sub_b2[t];
    if (t == 64) sRB2 = rate_b2[0];
    __syncthreads();

    int r = blockIdx.x * 256 + t;
    if (r >= NRXN) return;
    int n = cnt[r];
    int base = offset[r];
    float fn = (float)n;

    float h0 = fn * sB2[0], h1 = fn * sB2[1], h2 = fn * sB2[2], h3 = fn * sB2[3];
    float h4 = fn * sB2[4], h5 = fn * sB2[5], h6 = fn * sB2[6], h7 = fn * sB2[7];
    float exs = 0.f;
    for (int i = 0; i < n; ++i) {
        int e = slot_edge[base + i];
        const float4* mp = (const float4*)&msg[(size_t)e * 8];
        float4 a = mp[0], b = mp[1];
        h0 += a.x; h1 += a.y; h2 += a.z; h3 += a.w;
        h4 += b.x; h5 += b.y; h6 += b.z; h7 += b.w;
        exs += ext_e[e];
    }

    float acc = sRB2;
    #pragma unroll 4
    for (int j = 0; j < 64; ++j) {
        float z = sRB1[j];
        z = fmaf(h0, sR1[j],       z);
        z = fmaf(h1, sR1[64 + j],  z);
        z = fmaf(h2, sR1[128 + j], z);
        z = fmaf(h3, sR1[192 + j], z);
        z = fmaf(h4, sR1[256 + j], z);
        z = fmaf(h5, sR1[320 + j], z);
        z = fmaf(h6, sR1[384 + j], z);
        z = fmaf(h7, sR1[448 + j], z);
        acc = fmaf(fast_tanh(z), sR2[j], acc);
    }
    float nmax = fmaxf(fn, 1.0f);
    float ext_mean = 2.0f * exs * __builtin_amdgcn_rcpf(nmax);
    float kk = exp2f(log_k[r] * LOG2_10);
    float vr = kk * ext_mean * acc;
    v[r] = vr;

    // consumption scatter (pre-limit v, per reference)
    float cterm = vr * DT_C;
    for (int i = 0; i < n; ++i) {
        int e = slot_edge[base + i];
        atomicAdd(&total[met_sub[e]], sto_sub[e] * cterm);
    }
}

// ---- 7. per-metabolite scale + out init ------------------------------------
__global__ __launch_bounds__(256) void k_met(
    const float* __restrict__ x, const float* __restrict__ total,
    float* __restrict__ met_scale, float* __restrict__ out)
{
    int m = blockIdx.x * 256 + threadIdx.x;
    if (m >= NMET) return;
    float c = x[(size_t)m * 8 + 3];
    float tot = total[m];
    float ms = 1.0f;
    if (tot > 1e-12f) ms = fminf(c / tot, 1.0f);
    met_scale[m] = ms;
    out[m] = -HOMEO_C * (c - C_TARGET);
}

// ---- 8. per-reaction min over edges + v scale ------------------------------
__global__ __launch_bounds__(256) void k_rscale(
    const int* __restrict__ cnt, const int* __restrict__ offset,
    const int* __restrict__ slot_edge, const int* __restrict__ met_sub,
    const float* __restrict__ met_scale, float* __restrict__ v)
{
    int r = blockIdx.x * 256 + threadIdx.x;
    if (r >= NRXN) return;
    int n = cnt[r];
    int base = offset[r];
    float ms = 1.0f;
    for (int i = 0; i < n; ++i) {
        int e = slot_edge[base + i];
        ms = fminf(ms, met_scale[met_sub[e]]);
    }
    v[r] *= ms;
}

// ---- 9. final scatter-add --------------------------------------------------
__global__ __launch_bounds__(256) void k_contrib(
    const int* __restrict__ met_all, const int* __restrict__ rxn_all,
    const float* __restrict__ sto_all, const float* __restrict__ v,
    float* __restrict__ out)
{
    int e = blockIdx.x * 256 + threadIdx.x;
    if (e >= EALL) return;
    atomicAdd(&out[met_all[e]], sto_all[e] * v[rxn_all[e]]);
}

extern "C" void kernel_launch(void* const* d_in, const int* in_sizes, int n_in,
                              void* d_out, int out_size, void* d_ws, size_t ws_size,
                              hipStream_t stream) {
    const float* x       = (const float*)d_in[0];
    const int*   met_sub = (const int*)  d_in[1];
    const int*   rxn_sub = (const int*)  d_in[2];
    const float* sto_sub = (const float*)d_in[3];
    const int*   met_all = (const int*)  d_in[4];
    const int*   rxn_all = (const int*)  d_in[5];
    const float* sto_all = (const float*)d_in[6];
    const float* sub_w1  = (const float*)d_in[7];
    const float* sub_b1  = (const float*)d_in[8];
    const float* sub_w2  = (const float*)d_in[9];
    const float* sub_b2  = (const float*)d_in[10];
    const float* rate_w1 = (const float*)d_in[11];
    const float* rate_b1 = (const float*)d_in[12];
    const float* rate_w2 = (const float*)d_in[13];
    const float* rate_b2 = (const float*)d_in[14];
    const float* log_k   = (const float*)d_in[15];

    char* ws = (char*)d_ws;
    int*   cnt       = (int*)ws;                         // NRXN   [zeroed]
    float* total     = (float*)(cnt + NRXN);             // NMET   [zeroed]
    int*   rank      = (int*)(total + NMET);             // ESUB
    int*   offset    = rank + ESUB;                      // NRXN
    int*   bsum      = offset + NRXN;                    // 2048
    int*   boff      = bsum + 2048;                      // 2048
    int*   slot_edge = boff + 2048;                      // ESUB
    float* msg       = (float*)(slot_edge + ESUB);       // ESUB*8
    float* ext_e     = msg + (size_t)ESUB * 8;           // ESUB
    float* v         = ext_e + ESUB;                     // NRXN
    float* met_scale = v + NRXN;                         // NMET
    float* out       = (float*)d_out;

    // zero atomic accumulators: cnt + total are contiguous
    hipMemsetAsync(d_ws, 0, (size_t)(NRXN + NMET) * sizeof(int), stream);

    dim3 blk(256);
    k_hist_msg<<<dim3((ESUB + 255) / 256), blk, 0, stream>>>(
        x, met_sub, rxn_sub, sto_sub, sub_w1, sub_b1, sub_w2,
        cnt, rank, msg, ext_e);
    k_bsum<<<dim3(NBLK), blk, 0, stream>>>(cnt, bsum);
    k_scan_top<<<dim3(1), blk, 0, stream>>>(bsum, boff, NBLK);
    k_offsets<<<dim3(NBLK), blk, 0, stream>>>(cnt, boff, offset);
    k_scatter<<<dim3((ESUB + 255) / 256), blk, 0, stream>>>(
        rxn_sub, offset, rank, slot_edge);
    k_rxn3<<<dim3((NRXN + 255) / 256), blk, 0, stream>>>(
        cnt, offset, slot_edge, msg, ext_e, met_sub, sto_sub, sub_b2,
        rate_w1, rate_b1, rate_w2, rate_b2, log_k, v, total);
    k_met<<<dim3((NMET + 255) / 256), blk, 0, stream>>>(x, total, met_scale, out);
    k_rscale<<<dim3((NRXN + 255) / 256), blk, 0, stream>>>(
        cnt, offset, slot_edge, met_sub, met_scale, v);
    k_contrib<<<dim3((EALL + 255) / 256), blk, 0, stream>>>(
        met_all, rxn_all, sto_all, v, out);
}